// Round 3
// baseline (337.440 us; speedup 1.0000x reference)
//
#include <hip/hip_runtime.h>
#include <hip/hip_bf16.h>

typedef __bf16 bf16_t;
typedef __bf16 bf16x8 __attribute__((ext_vector_type(8)));
typedef float f32x16 __attribute__((ext_vector_type(16)));

// ---------------------------------------------------------------------------
// fused fp32 -> bf16 cast for 3 arrays (one launch; memory-bound)
// ---------------------------------------------------------------------------
__global__ __launch_bounds__(256) void cast3_f32_to_bf16(
    const float* __restrict__ a, bf16_t* __restrict__ ao, int na8,
    const float* __restrict__ b, bf16_t* __restrict__ bo, int nb8,
    const float* __restrict__ c, bf16_t* __restrict__ co, int nc8) {
  int i = blockIdx.x * blockDim.x + threadIdx.x;
  const float* in;
  bf16_t* out;
  int j;
  if (i < na8) {
    in = a; out = ao; j = i;
  } else if (i < na8 + nb8) {
    in = b; out = bo; j = i - na8;
  } else if (i < na8 + nb8 + nc8) {
    in = c; out = co; j = i - na8 - nb8;
  } else {
    return;
  }
  const float4* in4 = (const float4*)in;
  float4 f0 = in4[2 * j];
  float4 f1 = in4[2 * j + 1];
  bf16x8 o;
  o[0] = (bf16_t)f0.x; o[1] = (bf16_t)f0.y;
  o[2] = (bf16_t)f0.z; o[3] = (bf16_t)f0.w;
  o[4] = (bf16_t)f1.x; o[5] = (bf16_t)f1.y;
  o[6] = (bf16_t)f1.z; o[7] = (bf16_t)f1.w;
  ((bf16x8*)out)[j] = o;
}

// ---------------------------------------------------------------------------
// async global->LDS, 16B per lane. LDS dest = wave-uniform base + lane*16.
// ---------------------------------------------------------------------------
__device__ __forceinline__ void gload_lds16(const bf16_t* g, bf16_t* l) {
  __builtin_amdgcn_global_load_lds(
      (const __attribute__((address_space(1))) void*)g,
      (__attribute__((address_space(3))) void*)l,
      16, 0, 0);
}

// ---------------------------------------------------------------------------
// C[M,N] = A[M,K] * B[N,K]^T + bias[N], optional fused swish-poly.
// 256x128 block tile, BK=32, 4 waves (2x2), wave tile 128x64 via
// mfma_f32_32x32x16_bf16 (4 A-frags x 2 B-frags, acc 8 x f32x16).
// Rationale: the m97-family structure is LDS-pipe-bound; wave 128x64 cuts
// ds_read bytes/FLOP 25% vs 64x64 (0.023 vs 0.031 B/FLOP).
// Double-buffered LDS (48 KB), ONE barrier per iter; the vmcnt(0) drain at
// the barrier covers loads issued a full compute-phase earlier.
// XOR chunk swizzle: LDS rows of 32 elems = 4 x 16B chunks; physical chunk =
// logical ^ (row & 3) -> both A/B frag reads hit the b128 8-cycle floor.
// SWISH=true -> Cout bf16 (swish(h)); SWISH=false -> Cout fp32 (h).
// Requires: M%256==0, N%128==0, K%32==0, K/32>=2.
// ---------------------------------------------------------------------------
template <bool SWISH>
__global__ __launch_bounds__(256, 2) void gemm_bt(
    const bf16_t* __restrict__ A, const bf16_t* __restrict__ B,
    const float* __restrict__ bias, void* __restrict__ Cout,
    int M, int N, int K, int XW, int px, int py) {
  const int tid = threadIdx.x;
  const int wave = tid >> 6;
  const int lane = tid & 63;

  // ---- XCD-aware block swizzle (bid%8 = XCD round-robin assumption) ----
  const int bid = blockIdx.x;
  const int xcd = bid & 7;
  const int idx = bid >> 3;
  const int cx = xcd % XW;
  const int cy = xcd / XW;
  const int bx = cx * px + idx % px;
  const int by = cy * py + idx / px;
  const int tileM = by << 8;  // 256 rows
  const int tileN = bx << 7;  // 128 cols

  __shared__ __align__(16) bf16_t sA[2 * 256 * 32];  // 32 KB
  __shared__ __align__(16) bf16_t sB[2 * 128 * 32];  // 16 KB

  // ---- staging: lane -> 16 rows/load, phys chunk = lane&3,
  //      global chunk = (lane&3) ^ ((lane>>2)&3)  (matches read-side swizzle)
  const int lrow = lane >> 2;                   // 0..15
  const int clog = (lane & 3) ^ (lrow & 3);
  const bf16_t* gA = A + (size_t)(tileM + wave * 64 + lrow) * K + clog * 8;
  const bf16_t* gB = B + (size_t)(tileN + wave * 32 + lrow) * K + clog * 8;
  bf16_t* lA = sA + (wave * 64) * 32;           // wave-uniform base
  bf16_t* lB = sB + (wave * 32) * 32;

  // ---- fragment offsets (elements into sA/sB, buffer 0) ----
  // A-op 32x32x16: row = lane&31, k = (lane>>5)*8 + j; phys chunk ^= row&3
  const int wr = wave >> 1, wc = wave & 1;
  const int cswz = (((lane >> 5) ^ (lane & 3)) << 3);
  int offA[4], offB[2];
#pragma unroll
  for (int i = 0; i < 4; ++i)
    offA[i] = (wr * 128 + i * 32 + (lane & 31)) * 32 + cswz;
#pragma unroll
  for (int j = 0; j < 2; ++j)
    offB[j] = (wc * 64 + j * 32 + (lane & 31)) * 32 + cswz;

  f32x16 acc[4][2] = {};

  const int niter = K >> 5;

  // ---- prologue: stage iter 0 into buffer 0 ----
#pragma unroll
  for (int r = 0; r < 4; ++r)
    gload_lds16(gA + (size_t)(r * 16) * K, lA + r * 16 * 32);
#pragma unroll
  for (int r = 0; r < 2; ++r)
    gload_lds16(gB + (size_t)(r * 16) * K, lB + r * 16 * 32);

  for (int it = 0; it < niter; ++it) {
    __syncthreads();  // drains my buf[p] loads (issued one full iter ago)
    const int p = it & 1;
    if (it + 1 < niter) {
      const int kt = (it + 1) << 5;
      const int q = p ^ 1;
#pragma unroll
      for (int r = 0; r < 4; ++r)
        gload_lds16(gA + kt + (size_t)(r * 16) * K,
                    lA + q * (256 * 32) + r * 16 * 32);
#pragma unroll
      for (int r = 0; r < 2; ++r)
        gload_lds16(gB + kt + (size_t)(r * 16) * K,
                    lB + q * (128 * 32) + r * 16 * 32);
    }
    const bf16_t* bA = sA + p * (256 * 32);
    const bf16_t* bB = sB + p * (128 * 32);
    bf16x8 af[2][4], bg[2][2];
#pragma unroll
    for (int s = 0; s < 2; ++s) {
      const int sx = s << 4;  // kstep 1: chunk bit1 flip = element-offset ^16
#pragma unroll
      for (int i = 0; i < 4; ++i)
        af[s][i] = *(const bf16x8*)(bA + (offA[i] ^ sx));
#pragma unroll
      for (int j = 0; j < 2; ++j)
        bg[s][j] = *(const bf16x8*)(bB + (offB[j] ^ sx));
    }
#pragma unroll
    for (int s = 0; s < 2; ++s)
#pragma unroll
      for (int i = 0; i < 4; ++i)
#pragma unroll
        for (int j = 0; j < 2; ++j)
          acc[i][j] = __builtin_amdgcn_mfma_f32_32x32x16_bf16(
              af[s][i], bg[s][j], acc[i][j], 0, 0, 0);
  }

  // ---- epilogue: 32x32 C/D: col = lane&31, row = (r&3)+8*(r>>2)+4*(lane>>5)
  const int halfsel = (lane >> 5) << 2;
#pragma unroll
  for (int i = 0; i < 4; ++i) {
    const int row0 = tileM + wr * 128 + i * 32 + halfsel;
#pragma unroll
    for (int j = 0; j < 2; ++j) {
      const int col = tileN + wc * 64 + j * 32 + (lane & 31);
      const float bv = bias[col];
#pragma unroll
      for (int r = 0; r < 16; ++r) {
        const int row = row0 + (r & 3) + ((r >> 2) << 3);
        float h = acc[i][j][r] + bv;
        if constexpr (SWISH) {
          float h3 = h * h * h;
          float sw = h * (0.5f + 0.25f * h - 0.0208f * h3);
          ((bf16_t*)Cout)[(size_t)row * N + col] = (bf16_t)sw;
        } else {
          ((float*)Cout)[(size_t)row * N + col] = h;
        }
      }
    }
  }
}

// ---------------------------------------------------------------------------
// launch
// ---------------------------------------------------------------------------
extern "C" void kernel_launch(void* const* d_in, const int* in_sizes, int n_in,
                              void* d_out, int out_size, void* d_ws,
                              size_t ws_size, hipStream_t stream) {
  const float* X  = (const float*)d_in[0];  // [B,S,D] = [M,D]
  const float* W1 = (const float*)d_in[1];  // [F,D]
  const float* b1 = (const float*)d_in[2];  // [F]
  const float* W2 = (const float*)d_in[3];  // [D,F]
  const float* b2 = (const float*)d_in[4];  // [D]
  float* out = (float*)d_out;               // [M,D]

  const int F = in_sizes[2];      // 4096
  const int D = in_sizes[4];      // 1024
  const int M = in_sizes[0] / D;  // 8192

  // workspace layout (bf16): Xb[M*D] | W1b[F*D] | W2b[D*F] | SW[M*F]
  bf16_t* Xb  = (bf16_t*)d_ws;
  bf16_t* W1b = Xb + (size_t)M * D;
  bf16_t* W2b = W1b + (size_t)F * D;
  bf16_t* SW  = W2b + (size_t)D * F;

  const int nX = (M * D) / 8, nW1 = (F * D) / 8, nW2 = (D * F) / 8;
  const int nTot = nX + nW1 + nW2;
  cast3_f32_to_bf16<<<(nTot + 255) / 256, 256, 0, stream>>>(
      X, Xb, nX, W1, W1b, nW1, W2, W2b, nW2);

  // GEMM1: SW[M,F] = swish(Xb @ W1b^T + b1)  (bf16 out)
  // grid: gy = 8192/256 = 32, gx = 4096/128 = 32 -> 1024 blocks (4/CU)
  // XCDs 4x2: px=8, py=16 (B-slab 2 MB L2-resident; x-fastest reuses A-tile)
  {
    const int gx = F / 128, gy = M / 256;
    const int XW = 4, XH = 2;
    const int px = gx / XW, py = gy / XH;
    gemm_bt<true><<<gx * gy, 256, 0, stream>>>(
        Xb, W1b, b1, (void*)SW, M, F, D, XW, px, py);
  }

  // GEMM2: out[M,D] = SW @ W2b^T + b2        (fp32 out)
  // grid: gy = 32, gx = 1024/128 = 8 -> 256 blocks (exactly 1/CU; dbuf
  // pipeline carries the latency hiding). XCDs 8x1: px=1 -> each XCD owns
  // one 128-col strip: B-slab 1 MB L2-resident, A streamed once per XCD.
  {
    const int gx = D / 128, gy = M / 256;
    const int XW = 8, XH = 1;
    const int px = gx / XW, py = gy / XH;
    gemm_bt<false><<<gx * gy, 256, 0, stream>>>(
        SW, W2b, b2, (void*)out, M, D, F, XW, px, py);
  }
}

// Round 4
// 301.104 us; speedup vs baseline: 1.1207x; 1.1207x over previous
//
#include <hip/hip_runtime.h>
#include <hip/hip_bf16.h>

typedef __bf16 bf16_t;
typedef __bf16 bf16x8 __attribute__((ext_vector_type(8)));
typedef float f32x16 __attribute__((ext_vector_type(16)));

// ---------------------------------------------------------------------------
// fused fp32 -> bf16 cast for 3 arrays (one launch; memory-bound)
// ---------------------------------------------------------------------------
__global__ __launch_bounds__(256) void cast3_f32_to_bf16(
    const float* __restrict__ a, bf16_t* __restrict__ ao, int na8,
    const float* __restrict__ b, bf16_t* __restrict__ bo, int nb8,
    const float* __restrict__ c, bf16_t* __restrict__ co, int nc8) {
  int i = blockIdx.x * blockDim.x + threadIdx.x;
  const float* in;
  bf16_t* out;
  int j;
  if (i < na8) {
    in = a; out = ao; j = i;
  } else if (i < na8 + nb8) {
    in = b; out = bo; j = i - na8;
  } else if (i < na8 + nb8 + nc8) {
    in = c; out = co; j = i - na8 - nb8;
  } else {
    return;
  }
  const float4* in4 = (const float4*)in;
  float4 f0 = in4[2 * j];
  float4 f1 = in4[2 * j + 1];
  bf16x8 o;
  o[0] = (bf16_t)f0.x; o[1] = (bf16_t)f0.y;
  o[2] = (bf16_t)f0.z; o[3] = (bf16_t)f0.w;
  o[4] = (bf16_t)f1.x; o[5] = (bf16_t)f1.y;
  o[6] = (bf16_t)f1.z; o[7] = (bf16_t)f1.w;
  ((bf16x8*)out)[j] = o;
}

// ---------------------------------------------------------------------------
// async global->LDS, 16B per lane. LDS dest = wave-uniform base + lane*16.
// ---------------------------------------------------------------------------
__device__ __forceinline__ void gload_lds16(const bf16_t* g, bf16_t* l) {
  __builtin_amdgcn_global_load_lds(
      (const __attribute__((address_space(1))) void*)g,
      (__attribute__((address_space(3))) void*)l,
      16, 0, 0);
}

// ---------------------------------------------------------------------------
// C[M,N] = A[M,K] * B[N,K]^T + bias[N], optional fused swish-poly.
// 256x128 block tile, BK=32, 4 waves (2x2), wave tile 128x64 via
// mfma_f32_32x32x16_bf16 (4 A-frags x 2 B-frags/kstep, acc 8 x f32x16).
// LDS rows = 32 elems = 64 B. Granule(16B unit) = (4*row + chunk) mod 8.
// Swizzle: phys_chunk = logical ^ ((row>>1)&3) -> 8 consecutive rows cover
// all 8 granules (conflict-free at quarter-wave granularity; fixes R3's
// logical^(row&3) bug which confined even rows to granules 0-3).
// Staging lane l: row base+(l>>2), phys chunk l&3 -> global chunk
// (l&3)^((l>>3)&3)   [since bits 2:1 of row = (l>>3)&3; bases are %8==0].
// Double-buffered LDS (48 KB), ONE barrier/iter: DMA for iter+1 issued
// before iter's compute, drained by the NEXT barrier's vmcnt(0).
// SWISH=true -> Cout bf16 (swish(h)); SWISH=false -> Cout fp32 (h).
// Requires: M%256==0, N%128==0, K%32==0, K/32>=2.
// ---------------------------------------------------------------------------
template <bool SWISH>
__global__ __launch_bounds__(256, 2) void gemm_bt(
    const bf16_t* __restrict__ A, const bf16_t* __restrict__ B,
    const float* __restrict__ bias, void* __restrict__ Cout,
    int M, int N, int K, int XW, int px, int py) {
  const int tid = threadIdx.x;
  const int wave = tid >> 6;
  const int lane = tid & 63;

  // ---- XCD-aware block swizzle (bid%8 = XCD round-robin assumption) ----
  const int bid = blockIdx.x;
  const int xcd = bid & 7;
  const int idx = bid >> 3;
  const int cx = xcd % XW;
  const int cy = xcd / XW;
  const int bx = cx * px + idx % px;
  const int by = cy * py + idx / px;
  const int tileM = by << 8;  // 256 rows
  const int tileN = bx << 7;  // 128 cols

  __shared__ __align__(16) bf16_t sA[2 * 256 * 32];  // 32 KB
  __shared__ __align__(16) bf16_t sB[2 * 128 * 32];  // 16 KB

  // ---- staging: per round 64 rows (wave w: rows w*16..w*16+15) ----
  const int srow = (wave << 4) + (lane >> 2);            // 0..63
  const int gchunk = (lane & 3) ^ ((lane >> 3) & 3);     // swizzled global col
  const bf16_t* gA = A + (size_t)(tileM + srow) * K + gchunk * 8;
  const bf16_t* gB = B + (size_t)(tileN + srow) * K + gchunk * 8;
  bf16_t* lA = sA + (size_t)(wave << 4) * 32;  // wave-uniform base
  bf16_t* lB = sB + (size_t)(wave << 4) * 32;

  // ---- fragment offsets (elements, buffer 0) ----
  // A-op 32x32x16: row = lane&31, k = kstep*16 + (lane>>5)*8 + j
  // logical chunk = kstep*2 + (lane>>5); phys = logical ^ ((row>>1)&3)
  // bits 2:1 of frag row = (lane>>1)&3  (frag bases are multiples of 32)
  const int wr = wave >> 1, wc = wave & 1;
  const int frow = lane & 31;
  const int pbase = (((lane >> 5) ^ ((lane >> 1) & 3)) << 3);  // kstep0
  int offA[4], offB[2];
#pragma unroll
  for (int i = 0; i < 4; ++i)
    offA[i] = (wr * 128 + i * 32 + frow) * 32 + pbase;
#pragma unroll
  for (int j = 0; j < 2; ++j)
    offB[j] = (wc * 64 + j * 32 + frow) * 32 + pbase;
  // kstep 1: logical chunk += 2 -> phys ^= 2 -> element offset ^= 16

  f32x16 acc[4][2] = {};

  const int niter = K >> 5;

  // ---- prologue: stage iter 0 into buffer 0 ----
#pragma unroll
  for (int r = 0; r < 4; ++r)
    gload_lds16(gA + (size_t)(r * 64) * K, lA + r * 64 * 32);
#pragma unroll
  for (int r = 0; r < 2; ++r)
    gload_lds16(gB + (size_t)(r * 64) * K, lB + r * 64 * 32);

  for (int it = 0; it < niter; ++it) {
    __syncthreads();  // drains buf[it&1] DMA (issued one full iter ago)
    const int p = it & 1;
    if (it + 1 < niter) {
      const int kt = (it + 1) << 5;
      const int q = p ^ 1;
#pragma unroll
      for (int r = 0; r < 4; ++r)
        gload_lds16(gA + kt + (size_t)(r * 64) * K,
                    lA + q * (256 * 32) + r * 64 * 32);
#pragma unroll
      for (int r = 0; r < 2; ++r)
        gload_lds16(gB + kt + (size_t)(r * 64) * K,
                    lB + q * (128 * 32) + r * 64 * 32);
    }
    const bf16_t* bA = sA + p * (256 * 32);
    const bf16_t* bB = sB + p * (128 * 32);
#pragma unroll
    for (int s = 0; s < 2; ++s) {
      const int sx = s << 4;
      bf16x8 af[4], bg[2];
#pragma unroll
      for (int i = 0; i < 4; ++i)
        af[i] = *(const bf16x8*)(bA + (offA[i] ^ sx));
#pragma unroll
      for (int j = 0; j < 2; ++j)
        bg[j] = *(const bf16x8*)(bB + (offB[j] ^ sx));
#pragma unroll
      for (int i = 0; i < 4; ++i)
#pragma unroll
        for (int j = 0; j < 2; ++j)
          acc[i][j] = __builtin_amdgcn_mfma_f32_32x32x16_bf16(
              af[i], bg[j], acc[i][j], 0, 0, 0);
    }
  }

  // ---- epilogue: 32x32 C/D: col = lane&31, row = (r&3)+8*(r>>2)+4*(lane>>5)
  const int halfsel = (lane >> 5) << 2;
#pragma unroll
  for (int i = 0; i < 4; ++i) {
    const int row0 = tileM + wr * 128 + i * 32 + halfsel;
#pragma unroll
    for (int j = 0; j < 2; ++j) {
      const int col = tileN + wc * 64 + j * 32 + (lane & 31);
      const float bv = bias[col];
#pragma unroll
      for (int r = 0; r < 16; ++r) {
        const int row = row0 + (r & 3) + ((r >> 2) << 3);
        float h = acc[i][j][r] + bv;
        if constexpr (SWISH) {
          float h3 = h * h * h;
          float sw = h * (0.5f + 0.25f * h - 0.0208f * h3);
          ((bf16_t*)Cout)[(size_t)row * N + col] = (bf16_t)sw;
        } else {
          ((float*)Cout)[(size_t)row * N + col] = h;
        }
      }
    }
  }
}

// ---------------------------------------------------------------------------
// launch
// ---------------------------------------------------------------------------
extern "C" void kernel_launch(void* const* d_in, const int* in_sizes, int n_in,
                              void* d_out, int out_size, void* d_ws,
                              size_t ws_size, hipStream_t stream) {
  const float* X  = (const float*)d_in[0];  // [B,S,D] = [M,D]
  const float* W1 = (const float*)d_in[1];  // [F,D]
  const float* b1 = (const float*)d_in[2];  // [F]
  const float* W2 = (const float*)d_in[3];  // [D,F]
  const float* b2 = (const float*)d_in[4];  // [D]
  float* out = (float*)d_out;               // [M,D]

  const int F = in_sizes[2];      // 4096
  const int D = in_sizes[4];      // 1024
  const int M = in_sizes[0] / D;  // 8192

  // workspace layout (bf16): Xb[M*D] | W1b[F*D] | W2b[D*F] | SW[M*F]
  bf16_t* Xb  = (bf16_t*)d_ws;
  bf16_t* W1b = Xb + (size_t)M * D;
  bf16_t* W2b = W1b + (size_t)F * D;
  bf16_t* SW  = W2b + (size_t)D * F;

  const int nX = (M * D) / 8, nW1 = (F * D) / 8, nW2 = (D * F) / 8;
  const int nTot = nX + nW1 + nW2;
  cast3_f32_to_bf16<<<(nTot + 255) / 256, 256, 0, stream>>>(
      X, Xb, nX, W1, W1b, nW1, W2, W2b, nW2);

  // GEMM1: SW[M,F] = swish(Xb @ W1b^T + b1)  (bf16 out)
  // grid: gy = 8192/256 = 32, gx = 4096/128 = 32 -> 1024 blocks (4/CU)
  // XCDs 2x4: px=16, py=8 -> per-XCD footprint: A 2048 rows (4 MB),
  // B 2048 cols (4 MB); x-fastest keeps the 0.5 MB A-tile hot.
  {
    const int gx = F / 128, gy = M / 256;
    const int XW = 2, XH = 4;
    const int px = gx / XW, py = gy / XH;
    gemm_bt<true><<<gx * gy, 256, 0, stream>>>(
        Xb, W1b, b1, (void*)SW, M, F, D, XW, px, py);
  }

  // GEMM2: out[M,D] = SW @ W2b^T + b2        (fp32 out)
  // grid: gy = 32, gx = 1024/128 = 8 -> 256 blocks (1/CU; dbuf hides DMA).
  // XCDs 1x8 (y-partition): each XCD owns 4 y-tiles (1024 rows of SW,
  // streamed once); W2 (8 MB) refetched per XCD — small vs SW traffic.
  {
    const int gx = D / 128, gy = M / 256;
    const int XW = 1, XH = 8;
    const int px = gx / XW, py = gy / XH;
    gemm_bt<false><<<gx * gy, 256, 0, stream>>>(
        SW, W2b, b2, (void*)out, M, D, F, XW, px, py);
  }
}

// Round 5
// 271.983 us; speedup vs baseline: 1.2407x; 1.1071x over previous
//
#include <hip/hip_runtime.h>
#include <hip/hip_bf16.h>

typedef __bf16 bf16_t;
typedef __bf16 bf16x8 __attribute__((ext_vector_type(8)));
typedef float f32x16 __attribute__((ext_vector_type(16)));

// ---------------------------------------------------------------------------
// fused fp32 -> bf16 cast for 3 arrays (one launch; memory-bound)
// ---------------------------------------------------------------------------
__global__ __launch_bounds__(256) void cast3_f32_to_bf16(
    const float* __restrict__ a, bf16_t* __restrict__ ao, int na8,
    const float* __restrict__ b, bf16_t* __restrict__ bo, int nb8,
    const float* __restrict__ c, bf16_t* __restrict__ co, int nc8) {
  int i = blockIdx.x * blockDim.x + threadIdx.x;
  const float* in;
  bf16_t* out;
  int j;
  if (i < na8) {
    in = a; out = ao; j = i;
  } else if (i < na8 + nb8) {
    in = b; out = bo; j = i - na8;
  } else if (i < na8 + nb8 + nc8) {
    in = c; out = co; j = i - na8 - nb8;
  } else {
    return;
  }
  const float4* in4 = (const float4*)in;
  float4 f0 = in4[2 * j];
  float4 f1 = in4[2 * j + 1];
  bf16x8 o;
  o[0] = (bf16_t)f0.x; o[1] = (bf16_t)f0.y;
  o[2] = (bf16_t)f0.z; o[3] = (bf16_t)f0.w;
  o[4] = (bf16_t)f1.x; o[5] = (bf16_t)f1.y;
  o[6] = (bf16_t)f1.z; o[7] = (bf16_t)f1.w;
  ((bf16x8*)out)[j] = o;
}

// ---------------------------------------------------------------------------
// async global->LDS, 16B per lane. LDS dest = wave-uniform base + lane*16.
// ---------------------------------------------------------------------------
__device__ __forceinline__ void gload_lds16(const bf16_t* g, bf16_t* l) {
  __builtin_amdgcn_global_load_lds(
      (const __attribute__((address_space(1))) void*)g,
      (__attribute__((address_space(3))) void*)l,
      16, 0, 0);
}

// ---------------------------------------------------------------------------
// C[M,N] = A[M,K] * B[N,K]^T + bias[N], optional fused swish-poly.
//
// Block 256x128, BK=64, 4 waves (2x2), wave tile 128x64 via
// mfma_f32_32x32x16_bf16 (4 A-frags x 2 B-frags x 4 ksteps = 32 MFMA/iter).
//
// SINGLE-buffered LDS (48 KB), R2's proven 2-barrier schedule:
//   issue DMA -> barrier (drains vmcnt) -> frag reads + MFMA -> barrier.
// DMA writes and ds_reads NEVER overlap -> no write-vs-read bank collisions
// (R3/R4's dbuf produced 6.3M conflict cycles exactly from that overlap).
//
// LDS rows = 64 elems = 128 B = 8 chunks of 16B -> bank group == chunk
// (row-independent). Swizzle phys_chunk = logical ^ (row&7):
//   frag read lane l: row=l&31, logical = 2s + (l>>5) -> phys = logical^(l&7);
//   lanes 0..7 cover chunks 0..7 distinct -> conflict-free (as R2, measured 0).
//   staging lane l: row l>>3, phys chunk l&7 -> global chunk (l&7)^(l>>3).
// kstep s flips logical by 2s -> byte-XOR (s<<5) -> element-XOR (s<<4).
//
// SWISH=true -> Cout bf16 (swish(h)); SWISH=false -> Cout fp32 (h).
// Requires: M%256==0, N%128==0, K%64==0.
// ---------------------------------------------------------------------------
template <bool SWISH>
__global__ __launch_bounds__(256, 2) void gemm_bt(
    const bf16_t* __restrict__ A, const bf16_t* __restrict__ B,
    const float* __restrict__ bias, void* __restrict__ Cout,
    int M, int N, int K, int XW, int px, int py) {
  const int tid = threadIdx.x;
  const int wave = tid >> 6;
  const int lane = tid & 63;

  // ---- XCD-aware block swizzle (bid%8 = XCD round-robin assumption) ----
  const int bid = blockIdx.x;
  const int xcd = bid & 7;
  const int idx = bid >> 3;
  const int cx = xcd % XW;
  const int cy = xcd / XW;
  const int bx = cx * px + idx % px;
  const int by = cy * py + idx / px;
  const int tileM = by << 8;  // 256 rows
  const int tileN = bx << 7;  // 128 cols

  __shared__ __align__(16) bf16_t sA[256 * 64];  // 32 KB
  __shared__ __align__(16) bf16_t sB[128 * 64];  // 16 KB

  // ---- staging: 8 rows per gload instr (8 x 128B = 1KB) ----
  // wave stages A rows [wave*64, wave*64+64) in 8 gloads; B rows
  // [wave*32, wave*32+32) in 4 gloads.
  const int lrow = lane >> 3;                        // 0..7 within group
  const int gch = ((lane & 7) ^ lrow) << 3;          // swizzled global col
  const bf16_t* gA = A + (size_t)(tileM + (wave << 6) + lrow) * K + gch;
  const bf16_t* gB = B + (size_t)(tileN + (wave << 5) + lrow) * K + gch;
  bf16_t* lA = sA + (size_t)(wave << 6) * 64;  // wave-uniform base
  bf16_t* lB = sB + (size_t)(wave << 5) * 64;

  // ---- fragment offsets (elements), kstep 0 ----
  const int wr = wave >> 1, wc = wave & 1;
  const int frow = lane & 31;
  const int p0 = (((lane >> 5) ^ (lane & 7)) << 3);
  int offA[4], offB[2];
#pragma unroll
  for (int i = 0; i < 4; ++i)
    offA[i] = (wr * 128 + i * 32 + frow) * 64 + p0;
#pragma unroll
  for (int j = 0; j < 2; ++j)
    offB[j] = (wc * 64 + j * 32 + frow) * 64 + p0;

  f32x16 acc[4][2] = {};

  for (int kt = 0; kt < K; kt += 64) {
#pragma unroll
    for (int r = 0; r < 8; ++r)
      gload_lds16(gA + kt + (size_t)(r * 8) * K, lA + r * 8 * 64);
#pragma unroll
    for (int r = 0; r < 4; ++r)
      gload_lds16(gB + kt + (size_t)(r * 8) * K, lB + r * 8 * 64);
    __syncthreads();  // drains DMA; reads below never overlap DMA writes

#pragma unroll
    for (int s = 0; s < 4; ++s) {
      const int sx = s << 4;  // phys chunk ^= 2s  -> elem offset ^= s*16
      bf16x8 af[4], bg[2];
#pragma unroll
      for (int i = 0; i < 4; ++i)
        af[i] = *(const bf16x8*)(sA + (offA[i] ^ sx));
#pragma unroll
      for (int j = 0; j < 2; ++j)
        bg[j] = *(const bf16x8*)(sB + (offB[j] ^ sx));
#pragma unroll
      for (int i = 0; i < 4; ++i)
#pragma unroll
        for (int j = 0; j < 2; ++j)
          acc[i][j] = __builtin_amdgcn_mfma_f32_32x32x16_bf16(
              af[i], bg[j], acc[i][j], 0, 0, 0);
    }
    __syncthreads();  // protect LDS before next iter's DMA
  }

  // ---- epilogue: 32x32 C/D: col = lane&31, row = (r&3)+8*(r>>2)+4*(lane>>5)
  const int halfsel = (lane >> 5) << 2;
#pragma unroll
  for (int i = 0; i < 4; ++i) {
    const int row0 = tileM + wr * 128 + i * 32 + halfsel;
#pragma unroll
    for (int j = 0; j < 2; ++j) {
      const int col = tileN + wc * 64 + j * 32 + (lane & 31);
      const float bv = bias[col];
#pragma unroll
      for (int r = 0; r < 16; ++r) {
        const int row = row0 + (r & 3) + ((r >> 2) << 3);
        float h = acc[i][j][r] + bv;
        if constexpr (SWISH) {
          float h3 = h * h * h;
          float sw = h * (0.5f + 0.25f * h - 0.0208f * h3);
          ((bf16_t*)Cout)[(size_t)row * N + col] = (bf16_t)sw;
        } else {
          ((float*)Cout)[(size_t)row * N + col] = h;
        }
      }
    }
  }
}

// ---------------------------------------------------------------------------
// launch
// ---------------------------------------------------------------------------
extern "C" void kernel_launch(void* const* d_in, const int* in_sizes, int n_in,
                              void* d_out, int out_size, void* d_ws,
                              size_t ws_size, hipStream_t stream) {
  const float* X  = (const float*)d_in[0];  // [B,S,D] = [M,D]
  const float* W1 = (const float*)d_in[1];  // [F,D]
  const float* b1 = (const float*)d_in[2];  // [F]
  const float* W2 = (const float*)d_in[3];  // [D,F]
  const float* b2 = (const float*)d_in[4];  // [D]
  float* out = (float*)d_out;               // [M,D]

  const int F = in_sizes[2];      // 4096
  const int D = in_sizes[4];      // 1024
  const int M = in_sizes[0] / D;  // 8192

  // workspace layout (bf16): Xb[M*D] | W1b[F*D] | W2b[D*F] | SW[M*F]
  bf16_t* Xb  = (bf16_t*)d_ws;
  bf16_t* W1b = Xb + (size_t)M * D;
  bf16_t* W2b = W1b + (size_t)F * D;
  bf16_t* SW  = W2b + (size_t)D * F;

  const int nX = (M * D) / 8, nW1 = (F * D) / 8, nW2 = (D * F) / 8;
  const int nTot = nX + nW1 + nW2;
  cast3_f32_to_bf16<<<(nTot + 255) / 256, 256, 0, stream>>>(
      X, Xb, nX, W1, W1b, nW1, W2, W2b, nW2);

  // GEMM1: SW[M,F] = swish(Xb @ W1b^T + b1)  (bf16 out)
  // grid: gy = 8192/256 = 32, gx = 4096/128 = 32 -> 1024 blocks (4/CU)
  // XCDs 2x4: per-XCD footprint A 4 MB + B 4 MB (R4 measured 65 MB FETCH).
  {
    const int gx = F / 128, gy = M / 256;
    const int XW = 2, XH = 4;
    const int px = gx / XW, py = gy / XH;
    gemm_bt<true><<<gx * gy, 256, 0, stream>>>(
        Xb, W1b, b1, (void*)SW, M, F, D, XW, px, py);
  }

  // GEMM2: out[M,D] = SW @ W2b^T + b2        (fp32 out)
  // grid: gy = 32, gx = 1024/128 = 8 -> 256 blocks (1/CU).
  // XCDs 1x8 (y-partition): each XCD streams its SW strip once; W2 8 MB
  // cycles through L2.
  {
    const int gx = D / 128, gy = M / 256;
    const int XW = 1, XH = 8;
    const int px = gx / XW, py = gy / XH;
    gemm_bt<false><<<gx * gy, 256, 0, stream>>>(
        SW, W2b, b2, (void*)out, M, D, F, XW, px, py);
  }
}

// Round 6
// 268.419 us; speedup vs baseline: 1.2571x; 1.0133x over previous
//
#include <hip/hip_runtime.h>
#include <hip/hip_bf16.h>

typedef __bf16 bf16_t;
typedef __bf16 bf16x8 __attribute__((ext_vector_type(8)));
typedef float f32x16 __attribute__((ext_vector_type(16)));

// ---------------------------------------------------------------------------
// fused fp32 -> bf16 cast for 3 arrays (one launch; memory-bound)
// ---------------------------------------------------------------------------
__global__ __launch_bounds__(256) void cast3_f32_to_bf16(
    const float* __restrict__ a, bf16_t* __restrict__ ao, int na8,
    const float* __restrict__ b, bf16_t* __restrict__ bo, int nb8,
    const float* __restrict__ c, bf16_t* __restrict__ co, int nc8) {
  int i = blockIdx.x * blockDim.x + threadIdx.x;
  const float* in;
  bf16_t* out;
  int j;
  if (i < na8) {
    in = a; out = ao; j = i;
  } else if (i < na8 + nb8) {
    in = b; out = bo; j = i - na8;
  } else if (i < na8 + nb8 + nc8) {
    in = c; out = co; j = i - na8 - nb8;
  } else {
    return;
  }
  const float4* in4 = (const float4*)in;
  float4 f0 = in4[2 * j];
  float4 f1 = in4[2 * j + 1];
  bf16x8 o;
  o[0] = (bf16_t)f0.x; o[1] = (bf16_t)f0.y;
  o[2] = (bf16_t)f0.z; o[3] = (bf16_t)f0.w;
  o[4] = (bf16_t)f1.x; o[5] = (bf16_t)f1.y;
  o[6] = (bf16_t)f1.z; o[7] = (bf16_t)f1.w;
  ((bf16x8*)out)[j] = o;
}

// ---------------------------------------------------------------------------
// C[M,N] = A[M,K] * B[N,K]^T + bias[N], optional fused swish-poly.
//
// REGISTER-PREFETCH PIPELINE (R5 post-mortem: the 2-barrier global_load_lds
// structure is latency-bound — DMA issued immediately before its vmcnt(0)
// drain, nothing saturated: LDS 28%, MFMA 25%, HBM 12%).
// New K-loop: load tile k+1 -> VGPRs BEFORE computing tile k from LDS, then
// ds_write after compute. Prefetch distance = full compute phase (~600 cyc >
// L2 latency ~200-400), so the loads are landed by the time ds_write (or a
// conservative barrier vmcnt) consumes them.
//
// Tile 128x128, BK=64, 4 waves (2x2), wave tile 64x64 via
// mfma_f32_32x32x16_bf16 (2 A x 2 B frags x 4 ksteps = 16 MFMA/iter).
// LDS 32 KB single-buffer -> ~3 blocks/CU at ~150 VGPR.
//
// LDS rows = 64 elems = 128 B = 8 granules of 16 B; bank group == granule.
// Swizzle phys_chunk = logical ^ (row&7) (R5's, correctness-proven):
//   write: lane l -> row base+(l>>3), phys granule l&7; fetched global chunk
//          (l&7)^(l>>3).
//   read:  lane l row l&31, logical (s<<1)|(l>>5) -> phys xor (l&7);
//          lanes 0..7 cover granules 0..7 distinct.
// SWISH=true -> Cout bf16 (swish(h)); SWISH=false -> Cout fp32 (h).
// Requires: M%128==0, N%128==0, K%64==0.
// ---------------------------------------------------------------------------
template <bool SWISH>
__global__ __launch_bounds__(256, 2) void gemm_bt(
    const bf16_t* __restrict__ A, const bf16_t* __restrict__ B,
    const float* __restrict__ bias, void* __restrict__ Cout,
    int M, int N, int K, int XW, int px, int py) {
  const int tid = threadIdx.x;
  const int wave = tid >> 6;
  const int lane = tid & 63;

  // ---- XCD-aware block swizzle (bid%8 = XCD round-robin assumption) ----
  const int bid = blockIdx.x;
  const int xcd = bid & 7;
  const int idx = bid >> 3;
  const int cx = xcd % XW;
  const int cy = xcd / XW;
  const int bx = cx * px + idx % px;
  const int by = cy * py + idx / px;
  const int tileM = by << 7;  // 128 rows
  const int tileN = bx << 7;  // 128 cols

  __shared__ __align__(16) bf16_t sA[128 * 64];  // 16 KB
  __shared__ __align__(16) bf16_t sB[128 * 64];  // 16 KB

  // ---- staging geometry: wave w owns rows [w*32, w*32+32) of A and B ----
  // 4 loads per operand; load r covers rows w*32 + r*8 + (l>>3).
  const int lrow = lane >> 3;                  // 0..7
  const int gch = ((lane & 7) ^ lrow) << 3;    // swizzled global chunk (elems)
  const bf16_t* gA = A + (size_t)(tileM + (wave << 5) + lrow) * K + gch;
  const bf16_t* gB = B + (size_t)(tileN + (wave << 5) + lrow) * K + gch;
  bf16_t* wAp = sA + (size_t)(wave << 5) * 64 + (lane << 3);  // + r*512
  bf16_t* wBp = sB + (size_t)(wave << 5) * 64 + (lane << 3);

  // ---- fragment read offsets (elements), kstep 0 ----
  const int wr = wave >> 1, wc = wave & 1;
  const int frow = lane & 31;
  const int p0 = (((lane >> 5) ^ (lane & 7)) << 3);
  int offA[2], offB[2];
#pragma unroll
  for (int i = 0; i < 2; ++i)
    offA[i] = (wr * 64 + i * 32 + frow) * 64 + p0;
#pragma unroll
  for (int j = 0; j < 2; ++j)
    offB[j] = (wc * 64 + j * 32 + frow) * 64 + p0;

  f32x16 acc[2][2] = {};

  const int niter = K >> 6;

  // ---- prologue: tile 0 -> regs -> LDS ----
  bf16x8 vA[4], vB[4];
#pragma unroll
  for (int r = 0; r < 4; ++r) {
    vA[r] = *(const bf16x8*)(gA + (size_t)(r * 8) * K);
    vB[r] = *(const bf16x8*)(gB + (size_t)(r * 8) * K);
  }
#pragma unroll
  for (int r = 0; r < 4; ++r) {
    *(bf16x8*)(wAp + r * 512) = vA[r];
    *(bf16x8*)(wBp + r * 512) = vB[r];
  }
  __syncthreads();

  for (int it = 0; it < niter; ++it) {
    // ---- prefetch tile it+1 into registers (in flight during compute) ----
    if (it + 1 < niter) {
      const int kt = (it + 1) << 6;
#pragma unroll
      for (int r = 0; r < 4; ++r) {
        vA[r] = *(const bf16x8*)(gA + kt + (size_t)(r * 8) * K);
        vB[r] = *(const bf16x8*)(gB + kt + (size_t)(r * 8) * K);
      }
    }
    // ---- compute current tile from LDS ----
#pragma unroll
    for (int s = 0; s < 4; ++s) {
      const int sx = s << 4;  // phys granule ^= s<<1 -> elem offset ^= s*16
      bf16x8 a0 = *(const bf16x8*)(sA + (offA[0] ^ sx));
      bf16x8 a1 = *(const bf16x8*)(sA + (offA[1] ^ sx));
      bf16x8 b0 = *(const bf16x8*)(sB + (offB[0] ^ sx));
      bf16x8 b1 = *(const bf16x8*)(sB + (offB[1] ^ sx));
      acc[0][0] = __builtin_amdgcn_mfma_f32_32x32x16_bf16(a0, b0, acc[0][0], 0, 0, 0);
      acc[0][1] = __builtin_amdgcn_mfma_f32_32x32x16_bf16(a0, b1, acc[0][1], 0, 0, 0);
      acc[1][0] = __builtin_amdgcn_mfma_f32_32x32x16_bf16(a1, b0, acc[1][0], 0, 0, 0);
      acc[1][1] = __builtin_amdgcn_mfma_f32_32x32x16_bf16(a1, b1, acc[1][1], 0, 0, 0);
    }
    __syncthreads();  // all reads of current tile done before overwrite
    if (it + 1 < niter) {
#pragma unroll
      for (int r = 0; r < 4; ++r) {
        *(bf16x8*)(wAp + r * 512) = vA[r];
        *(bf16x8*)(wBp + r * 512) = vB[r];
      }
    }
    __syncthreads();  // writes visible before next compute
  }

  // ---- epilogue: 32x32 C/D: col = lane&31, row = (r&3)+8*(r>>2)+4*(lane>>5)
  const int halfsel = (lane >> 5) << 2;
#pragma unroll
  for (int i = 0; i < 2; ++i) {
    const int row0 = tileM + wr * 64 + i * 32 + halfsel;
#pragma unroll
    for (int j = 0; j < 2; ++j) {
      const int col = tileN + wc * 64 + j * 32 + (lane & 31);
      const float bv = bias[col];
#pragma unroll
      for (int r = 0; r < 16; ++r) {
        const int row = row0 + (r & 3) + ((r >> 2) << 3);
        float h = acc[i][j][r] + bv;
        if constexpr (SWISH) {
          float h3 = h * h * h;
          float sw = h * (0.5f + 0.25f * h - 0.0208f * h3);
          ((bf16_t*)Cout)[(size_t)row * N + col] = (bf16_t)sw;
        } else {
          ((float*)Cout)[(size_t)row * N + col] = h;
        }
      }
    }
  }
}

// ---------------------------------------------------------------------------
// launch
// ---------------------------------------------------------------------------
extern "C" void kernel_launch(void* const* d_in, const int* in_sizes, int n_in,
                              void* d_out, int out_size, void* d_ws,
                              size_t ws_size, hipStream_t stream) {
  const float* X  = (const float*)d_in[0];  // [B,S,D] = [M,D]
  const float* W1 = (const float*)d_in[1];  // [F,D]
  const float* b1 = (const float*)d_in[2];  // [F]
  const float* W2 = (const float*)d_in[3];  // [D,F]
  const float* b2 = (const float*)d_in[4];  // [D]
  float* out = (float*)d_out;               // [M,D]

  const int F = in_sizes[2];      // 4096
  const int D = in_sizes[4];      // 1024
  const int M = in_sizes[0] / D;  // 8192

  // workspace layout (bf16): Xb[M*D] | W1b[F*D] | W2b[D*F] | SW[M*F]
  bf16_t* Xb  = (bf16_t*)d_ws;
  bf16_t* W1b = Xb + (size_t)M * D;
  bf16_t* W2b = W1b + (size_t)F * D;
  bf16_t* SW  = W2b + (size_t)D * F;

  const int nX = (M * D) / 8, nW1 = (F * D) / 8, nW2 = (D * F) / 8;
  const int nTot = nX + nW1 + nW2;
  cast3_f32_to_bf16<<<(nTot + 255) / 256, 256, 0, stream>>>(
      X, Xb, nX, W1, W1b, nW1, W2, W2b, nW2);

  // GEMM1: SW[M,F] = swish(Xb @ W1b^T + b1)  (bf16 out)
  // grid: gy = 8192/128 = 64, gx = 4096/128 = 32 -> 2048 blocks (8/CU queue)
  // XCDs 2x4: per-XCD footprint A 4 MB + B 4 MB.
  {
    const int gx = F / 128, gy = M / 128;
    const int XW = 2, XH = 4;
    const int px = gx / XW, py = gy / XH;
    gemm_bt<true><<<gx * gy, 256, 0, stream>>>(
        Xb, W1b, b1, (void*)SW, M, F, D, XW, px, py);
  }

  // GEMM2: out[M,D] = SW @ W2b^T + b2        (fp32 out)
  // grid: gy = 64, gx = 1024/128 = 8 -> 512 blocks (2/CU).
  // XCDs 1x8 (y-partition): per-XCD SW strip read once; W2 via L2/L3.
  {
    const int gx = D / 128, gy = M / 128;
    const int XW = 1, XH = 8;
    const int px = gx / XW, py = gy / XH;
    gemm_bt<false><<<gx * gy, 256, 0, stream>>>(
        SW, W2b, b2, (void*)out, M, D, F, XW, px, py);
  }
}